// Round 3
// baseline (3227.065 us; speedup 1.0000x reference)
//
#include <hip/hip_runtime.h>
#include <hip/hip_bf16.h>

#define NN 40000
#define NE 640000
#define NG 2048
#define DD 128
#define NT 10
#define NL 5

// x[n][d] = sum_f atom_emb[f][x_atom[n][f]][d]
__global__ void k_atom(const int* __restrict__ xa, const float* __restrict__ emb,
                       float* __restrict__ x) {
    int n = blockIdx.x, d = threadIdx.x;
    __shared__ int idx[9];
    if (d < 9) idx[d] = xa[n * 9 + d];
    __syncthreads();
    float s = 0.f;
#pragma unroll
    for (int f = 0; f < 9; ++f) s += emb[(f * 64 + idx[f]) * DD + d];
    x[n * DD + d] = s;
}

// h = (1+eps_layer) * x   (init of aggregation buffer; scatter adds into it)
__global__ void k_scale(const float* __restrict__ x, const float* __restrict__ eps,
                        int layer, float* __restrict__ h) {
    int i = blockIdx.x * blockDim.x + threadIdx.x;
    float e = 1.f + eps[layer];
    h[i] = e * x[i];
}

// per edge: msg = relu(x[src] + bond_emb(attr)); h[dst] += msg
__global__ void k_edge(const int* __restrict__ ei, const int* __restrict__ ea,
                       const float* __restrict__ bemb,  // [3][8][D] for this layer
                       const float* __restrict__ x, float* __restrict__ h) {
    int e = blockIdx.x * 2 + (threadIdx.x >> 7);
    int d = threadIdx.x & (DD - 1);
    int src = ei[e];
    int dst = ei[NE + e];
    int a0 = ea[e * 3 + 0], a1 = ea[e * 3 + 1], a2 = ea[e * 3 + 2];
    float v = bemb[a0 * DD + d] + bemb[(8 + a1) * DD + d] + bemb[(16 + a2) * DD + d];
    v += x[src * DD + d];
    v = fmaxf(v, 0.f);
    atomicAdd(&h[dst * DD + d], v);
}

// Fused MLP: x = BNO(relu(BN1(h@W1+b1)) @ W2 + b2) (+relu unless last layer)
// One node per block, 256 threads. h1 row lives in LDS only.
__global__ void k_mlp(const float* __restrict__ h, const float* __restrict__ W1,
                      const float* __restrict__ b1, const float* __restrict__ g1,
                      const float* __restrict__ bt1, const float* __restrict__ m1,
                      const float* __restrict__ v1, const float* __restrict__ W2,
                      const float* __restrict__ b2_, const float* __restrict__ gO,
                      const float* __restrict__ btO, const float* __restrict__ mO,
                      const float* __restrict__ vO, int relu, float* __restrict__ x) {
    int n = blockIdx.x, t = threadIdx.x;  // t in [0,256)
    __shared__ float row[DD];
    __shared__ float mid[256];
    __shared__ float part[256];
    if (t < DD) row[t] = h[n * DD + t];
    __syncthreads();
    // GEMM1: mid[t] = relu(BN1(sum_k row[k]*W1[k][t] + b1[t]))
    float acc = 0.f;
#pragma unroll 8
    for (int k = 0; k < DD; ++k) acc = fmaf(row[k], W1[k * 256 + t], acc);
    acc += b1[t];
    float s1 = g1[t] * rsqrtf(v1[t] + 1e-5f);
    float o1 = (acc - m1[t]) * s1 + bt1[t];
    mid[t] = fmaxf(o1, 0.f);
    __syncthreads();
    // GEMM2 split-K: half 0 handles k in [0,128), half 1 k in [128,256)
    int half = t >> 7;
    int col = t & (DD - 1);
    const float* W2h = W2 + half * DD * DD;
    const float* midh = mid + half * DD;
    float acc2 = 0.f;
#pragma unroll 8
    for (int k = 0; k < DD; ++k) acc2 = fmaf(midh[k], W2h[k * DD + col], acc2);
    part[t] = acc2;
    __syncthreads();
    if (t < DD) {
        float a = part[t] + part[t + DD] + b2_[t];
        float s = gO[t] * rsqrtf(vO[t] + 1e-5f);
        float o = (a - mO[t]) * s + btO[t];
        if (relu) o = fmaxf(o, 0.f);
        x[n * DD + t] = o;
    }
}

__global__ void k_pool(const float* __restrict__ x, const int* __restrict__ batch,
                       float* __restrict__ sums, float* __restrict__ cnt) {
    int n = blockIdx.x, d = threadIdx.x;
    int g = batch[n];
    atomicAdd(&sums[g * DD + d], x[n * DD + d]);
    if (d == 0) atomicAdd(&cnt[g], 1.f);
}

__global__ void k_head(const float* __restrict__ sums, const float* __restrict__ cnt,
                       const float* __restrict__ Wp, const float* __restrict__ bp,
                       float* __restrict__ out) {
    int g = blockIdx.x;
    int d = threadIdx.x;
    __shared__ float p[DD];
    float c = fmaxf(cnt[g], 1.f);
    p[d] = sums[g * DD + d] / c;
    __syncthreads();
    if (d < NT) {
        float acc = bp[d];
#pragma unroll 8
        for (int k = 0; k < DD; ++k) acc = fmaf(p[k], Wp[k * NT + d], acc);
        out[g * NT + d] = acc;
    }
}

extern "C" void kernel_launch(void* const* d_in, const int* in_sizes, int n_in,
                              void* d_out, int out_size, void* d_ws, size_t ws_size,
                              hipStream_t stream) {
    const int* x_atom = (const int*)d_in[0];
    const int* edge_index = (const int*)d_in[1];
    const int* edge_attr = (const int*)d_in[2];
    const int* batch = (const int*)d_in[3];
    const float* atom_emb = (const float*)d_in[4];
    const float* bond_emb = (const float*)d_in[5];
    const float* eps = (const float*)d_in[6];
    const float* W1 = (const float*)d_in[7];
    const float* b1 = (const float*)d_in[8];
    const float* g1 = (const float*)d_in[9];
    const float* bt1 = (const float*)d_in[10];
    const float* m1 = (const float*)d_in[11];
    const float* v1 = (const float*)d_in[12];
    const float* W2 = (const float*)d_in[13];
    const float* b2 = (const float*)d_in[14];
    const float* gO = (const float*)d_in[15];
    const float* btO = (const float*)d_in[16];
    const float* mO = (const float*)d_in[17];
    const float* vO = (const float*)d_in[18];
    const float* Wp = (const float*)d_in[19];
    const float* bp = (const float*)d_in[20];

    float* x = (float*)d_ws;            // N*D        (20.48 MB)
    float* h = x + NN * DD;             // N*D        (20.48 MB)
    float* sums = h + NN * DD;          // G*D        (1.05 MB)
    float* cnt = sums + NG * DD;        // G          (8 KB)

    hipMemsetAsync(sums, 0, (NG * DD + NG) * sizeof(float), stream);
    k_atom<<<NN, DD, 0, stream>>>(x_atom, atom_emb, x);
    for (int i = 0; i < NL; ++i) {
        k_scale<<<(NN * DD) / 256, 256, 0, stream>>>(x, eps, i, h);
        k_edge<<<NE / 2, 256, 0, stream>>>(edge_index, edge_attr,
                                           bond_emb + (size_t)i * 3 * 8 * DD, x, h);
        k_mlp<<<NN, 256, 0, stream>>>(h, W1 + (size_t)i * DD * 256, b1 + i * 256,
                                      g1 + i * 256, bt1 + i * 256, m1 + i * 256,
                                      v1 + i * 256, W2 + (size_t)i * 256 * DD,
                                      b2 + i * DD, gO + i * DD, btO + i * DD,
                                      mO + i * DD, vO + i * DD,
                                      (i < NL - 1) ? 1 : 0, x);
    }
    k_pool<<<NN, DD, 0, stream>>>(x, batch, sums, cnt);
    k_head<<<NG, DD, 0, stream>>>(sums, cnt, Wp, bp, (float*)d_out);
}

// Round 4
// 1680.706 us; speedup vs baseline: 1.9201x; 1.9201x over previous
//
#include <hip/hip_runtime.h>
#include <hip/hip_bf16.h>

#define NN 40000
#define NE 640000
#define NG 2048
#define DD 128
#define NT 10
#define NL 5

typedef __attribute__((ext_vector_type(8))) short short8;
typedef __attribute__((ext_vector_type(4))) float f32x4;
typedef unsigned short ushort_t;

static __device__ __forceinline__ ushort_t f2b(float f) {
    return __bfloat16_as_ushort(__float2bfloat16(f));
}

// x[n][d] = sum_f atom_emb[f][x_atom[n][f]][d]
__global__ void k_atom(const int* __restrict__ xa, const float* __restrict__ emb,
                       float* __restrict__ x) {
    int n = blockIdx.x, d = threadIdx.x;
    __shared__ int idx[9];
    if (d < 9) idx[d] = xa[n * 9 + d];
    __syncthreads();
    float s = 0.f;
#pragma unroll
    for (int f = 0; f < 9; ++f) s += emb[(f * 64 + idx[f]) * DD + d];
    x[n * DD + d] = s;
}

// h = (1+eps_layer) * x   (init of aggregation buffer; scatter adds into it)
__global__ void k_scale(const float* __restrict__ x, const float* __restrict__ eps,
                        int layer, float* __restrict__ h) {
    int i = blockIdx.x * blockDim.x + threadIdx.x;
    float e = 1.f + eps[layer];
    h[i] = e * x[i];
}

// per edge: msg = relu(x[src] + bond_emb(attr)); h[dst] += msg
__global__ void k_edge(const int* __restrict__ ei, const int* __restrict__ ea,
                       const float* __restrict__ bemb,  // [3][8][D] for this layer
                       const float* __restrict__ x, float* __restrict__ h) {
    int e = blockIdx.x * 2 + (threadIdx.x >> 7);
    int d = threadIdx.x & (DD - 1);
    int src = ei[e];
    int dst = ei[NE + e];
    int a0 = ea[e * 3 + 0], a1 = ea[e * 3 + 1], a2 = ea[e * 3 + 2];
    float v = bemb[a0 * DD + d] + bemb[(8 + a1) * DD + d] + bemb[(16 + a2) * DD + d];
    v += x[src * DD + d];
    v = fmaxf(v, 0.f);
    atomicAdd(&h[dst * DD + d], v);
}

// Prepack W1/W2 (fp32) into bf16 B-fragment order for mfma_f32_16x16x32_bf16.
// W1P per layer: [nt<16][kk<4][lane<64][j<8], element = W1[k][n],
//   n = nt*16 + (lane&15), k = kk*32 + (lane>>4)*8 + j
// W2P per layer: [nt<8][kk<8][lane<64][j<8], element = W2[k][n]
__global__ void k_prep(const float* __restrict__ W1, const float* __restrict__ W2,
                       ushort_t* __restrict__ W1P, ushort_t* __restrict__ W2P) {
    int tid = blockIdx.x * 256 + threadIdx.x;  // < NL*65536
    int layer = tid >> 16;
    int r = tid & 65535;
    int half = r >> 15;
    int q = r & 32767;
    int j = q & 7;
    int lane = (q >> 3) & 63;
    if (half == 0) {
        int kk = (q >> 9) & 3;
        int nt = q >> 11;
        int n = nt * 16 + (lane & 15);
        int k = kk * 32 + (lane >> 4) * 8 + j;
        W1P[layer * 32768 + q] = f2b(W1[(layer * DD + k) * 256 + n]);
    } else {
        int kk = (q >> 9) & 7;
        int nt = q >> 12;
        int n = nt * 16 + (lane & 15);
        int k = kk * 32 + (lane >> 4) * 8 + j;
        W2P[layer * 32768 + q] = f2b(W2[(layer * 256 + k) * DD + n]);
    }
}

// Fused MLP on MFMA: x = BNO(relu(BN1(h@W1+b1)) @ W2 + b2) (+relu unless last)
// 16 nodes per block, 256 threads (4 waves).
__global__ void __launch_bounds__(256)
k_mlp_mfma(const float* __restrict__ h, const ushort_t* __restrict__ W1P,
           const ushort_t* __restrict__ W2P, const float* __restrict__ b1,
           const float* __restrict__ g1, const float* __restrict__ bt1,
           const float* __restrict__ m1, const float* __restrict__ v1,
           const float* __restrict__ b2_, const float* __restrict__ gO,
           const float* __restrict__ btO, const float* __restrict__ mO,
           const float* __restrict__ vO, int relu, float* __restrict__ x) {
    __shared__ ushort_t aS[16 * 136];   // 16 rows x 128 (pad +8 halfs: bank adv 4)
    __shared__ ushort_t mid[16 * 264];  // 16 rows x 256 (pad +8 halfs)
    int t = threadIdx.x;
    int wave = t >> 6, lane = t & 63;
    int row0 = blockIdx.x * 16;
    int lrow = lane & 15, quad = lane >> 4;

    // stage h tile as bf16
    for (int i = t; i < 2048; i += 256) {
        int r = i >> 7, c = i & 127;
        aS[r * 136 + c] = f2b(h[(row0 + r) * DD + c]);
    }
    __syncthreads();

    // GEMM1: 16x128 @ 128x256. Wave w covers cols [w*64, w*64+64) = 4 n-tiles.
    f32x4 acc1[4];
#pragma unroll
    for (int i = 0; i < 4; ++i) acc1[i] = (f32x4){0.f, 0.f, 0.f, 0.f};
#pragma unroll
    for (int kk = 0; kk < 4; ++kk) {
        short8 af = *(const short8*)&aS[lrow * 136 + kk * 32 + quad * 8];
#pragma unroll
        for (int i = 0; i < 4; ++i) {
            int nt = wave * 4 + i;
            short8 bf = *(const short8*)&W1P[((nt * 4 + kk) * 64 + lane) * 8];
            acc1[i] = __builtin_amdgcn_mfma_f32_16x16x32_bf16(af, bf, acc1[i], 0, 0, 0);
        }
    }
    // epilogue 1: BN1 + relu -> mid (bf16)
#pragma unroll
    for (int i = 0; i < 4; ++i) {
        int col = (wave * 4 + i) * 16 + lrow;
        float s1 = g1[col] * rsqrtf(v1[col] + 1e-5f);
        float sh = bt1[col] - (m1[col] - b1[col]) * s1;
#pragma unroll
        for (int r = 0; r < 4; ++r) {
            int row = quad * 4 + r;
            float o = acc1[i][r] * s1 + sh;
            mid[row * 264 + col] = f2b(fmaxf(o, 0.f));
        }
    }
    __syncthreads();

    // GEMM2: 16x256 @ 256x128. Wave w covers cols [w*32, w*32+32) = 2 n-tiles.
    f32x4 acc2[2];
#pragma unroll
    for (int i = 0; i < 2; ++i) acc2[i] = (f32x4){0.f, 0.f, 0.f, 0.f};
#pragma unroll
    for (int kk = 0; kk < 8; ++kk) {
        short8 af = *(const short8*)&mid[lrow * 264 + kk * 32 + quad * 8];
#pragma unroll
        for (int i = 0; i < 2; ++i) {
            int nt = wave * 2 + i;
            short8 bf = *(const short8*)&W2P[((nt * 8 + kk) * 64 + lane) * 8];
            acc2[i] = __builtin_amdgcn_mfma_f32_16x16x32_bf16(af, bf, acc2[i], 0, 0, 0);
        }
    }
    // epilogue 2: BNO (+relu) -> x (fp32)
#pragma unroll
    for (int i = 0; i < 2; ++i) {
        int col = (wave * 2 + i) * 16 + lrow;
        float s = gO[col] * rsqrtf(vO[col] + 1e-5f);
        float sh = btO[col] - (mO[col] - b2_[col]) * s;
#pragma unroll
        for (int r = 0; r < 4; ++r) {
            int row = quad * 4 + r;
            float o = acc2[i][r] * s + sh;
            if (relu) o = fmaxf(o, 0.f);
            x[(row0 + row) * DD + col] = o;
        }
    }
}

__global__ void k_pool(const float* __restrict__ x, const int* __restrict__ batch,
                       float* __restrict__ sums, float* __restrict__ cnt) {
    int n = blockIdx.x, d = threadIdx.x;
    int g = batch[n];
    atomicAdd(&sums[g * DD + d], x[n * DD + d]);
    if (d == 0) atomicAdd(&cnt[g], 1.f);
}

__global__ void k_head(const float* __restrict__ sums, const float* __restrict__ cnt,
                       const float* __restrict__ Wp, const float* __restrict__ bp,
                       float* __restrict__ out) {
    int g = blockIdx.x;
    int d = threadIdx.x;
    __shared__ float p[DD];
    float c = fmaxf(cnt[g], 1.f);
    p[d] = sums[g * DD + d] / c;
    __syncthreads();
    if (d < NT) {
        float acc = bp[d];
#pragma unroll 8
        for (int k = 0; k < DD; ++k) acc = fmaf(p[k], Wp[k * NT + d], acc);
        out[g * NT + d] = acc;
    }
}

extern "C" void kernel_launch(void* const* d_in, const int* in_sizes, int n_in,
                              void* d_out, int out_size, void* d_ws, size_t ws_size,
                              hipStream_t stream) {
    const int* x_atom = (const int*)d_in[0];
    const int* edge_index = (const int*)d_in[1];
    const int* edge_attr = (const int*)d_in[2];
    const int* batch = (const int*)d_in[3];
    const float* atom_emb = (const float*)d_in[4];
    const float* bond_emb = (const float*)d_in[5];
    const float* eps = (const float*)d_in[6];
    const float* W1 = (const float*)d_in[7];
    const float* b1 = (const float*)d_in[8];
    const float* g1 = (const float*)d_in[9];
    const float* bt1 = (const float*)d_in[10];
    const float* m1 = (const float*)d_in[11];
    const float* v1 = (const float*)d_in[12];
    const float* W2 = (const float*)d_in[13];
    const float* b2 = (const float*)d_in[14];
    const float* gO = (const float*)d_in[15];
    const float* btO = (const float*)d_in[16];
    const float* mO = (const float*)d_in[17];
    const float* vO = (const float*)d_in[18];
    const float* Wp = (const float*)d_in[19];
    const float* bp = (const float*)d_in[20];

    float* x = (float*)d_ws;            // N*D        (20.48 MB)
    float* h = x + NN * DD;             // N*D        (20.48 MB)
    float* sums = h + NN * DD;          // G*D        (1.05 MB)
    float* cnt = sums + NG * DD;        // G          (8 KB)
    ushort_t* W1P = (ushort_t*)(cnt + NG);   // L*32768 bf16 (320 KB)
    ushort_t* W2P = W1P + NL * 32768;        // L*32768 bf16 (320 KB)

    hipMemsetAsync(sums, 0, (NG * DD + NG) * sizeof(float), stream);
    k_prep<<<NL * 65536 / 256, 256, 0, stream>>>(W1, W2, W1P, W2P);
    k_atom<<<NN, DD, 0, stream>>>(x_atom, atom_emb, x);
    for (int i = 0; i < NL; ++i) {
        k_scale<<<(NN * DD) / 256, 256, 0, stream>>>(x, eps, i, h);
        k_edge<<<NE / 2, 256, 0, stream>>>(edge_index, edge_attr,
                                           bond_emb + (size_t)i * 3 * 8 * DD, x, h);
        k_mlp_mfma<<<NN / 16, 256, 0, stream>>>(
            h, W1P + (size_t)i * 32768, W2P + (size_t)i * 32768, b1 + i * 256,
            g1 + i * 256, bt1 + i * 256, m1 + i * 256, v1 + i * 256, b2 + i * DD,
            gO + i * DD, btO + i * DD, mO + i * DD, vO + i * DD,
            (i < NL - 1) ? 1 : 0, x);
    }
    k_pool<<<NN, DD, 0, stream>>>(x, batch, sums, cnt);
    k_head<<<NG, DD, 0, stream>>>(sums, cnt, Wp, bp, (float*)d_out);
}

// Round 5
// 968.803 us; speedup vs baseline: 3.3310x; 1.7348x over previous
//
#include <hip/hip_runtime.h>
#include <hip/hip_bf16.h>

#define NN 40000
#define NE 640000
#define NG 2048
#define DD 128
#define NT 10
#define NL 5

typedef __attribute__((ext_vector_type(8))) short short8;
typedef __attribute__((ext_vector_type(4))) float f32x4;
typedef unsigned short ushort_t;

static __device__ __forceinline__ ushort_t f2b(float f) {
    return __bfloat16_as_ushort(__float2bfloat16(f));
}

// x[n][d] = sum_f atom_emb[f][x_atom[n][f]][d]
__global__ void k_atom(const int* __restrict__ xa, const float* __restrict__ emb,
                       float* __restrict__ x) {
    int n = blockIdx.x, d = threadIdx.x;
    __shared__ int idx[9];
    if (d < 9) idx[d] = xa[n * 9 + d];
    __syncthreads();
    float s = 0.f;
#pragma unroll
    for (int f = 0; f < 9; ++f) s += emb[(f * 64 + idx[f]) * DD + d];
    x[n * DD + d] = s;
}

// ---------------- CSR build (once per launch, reused for all 5 layers) -----

__global__ void k_hist(const int* __restrict__ ei, int* __restrict__ deg) {
    int e = blockIdx.x * 256 + threadIdx.x;
    atomicAdd(&deg[ei[NE + e]], 1);
}

// block-local exclusive scan; off[i] = exclusive prefix within block
__global__ void k_scan1(const int* __restrict__ deg, int* __restrict__ off,
                        int* __restrict__ blksum) {
    int b = blockIdx.x, t = threadIdx.x;
    int i = b * 256 + t;
    __shared__ int s[256];
    int v = (i < NN) ? deg[i] : 0;
    s[t] = v;
    __syncthreads();
    for (int d = 1; d < 256; d <<= 1) {
        int add = (t >= d) ? s[t - d] : 0;
        __syncthreads();
        s[t] += add;
        __syncthreads();
    }
    if (i <= NN) off[i] = s[t] - v;
    if (t == 255) blksum[b] = s[255];
}

__global__ void k_scan2(int* __restrict__ blk) {  // blk[0..255]=sums, writes blk[256..511]
    int t = threadIdx.x;
    __shared__ int s[256];
    int v = blk[t];
    s[t] = v;
    __syncthreads();
    for (int d = 1; d < 256; d <<= 1) {
        int add = (t >= d) ? s[t - d] : 0;
        __syncthreads();
        s[t] += add;
        __syncthreads();
    }
    blk[256 + t] = s[t] - v;  // exclusive
}

__global__ void k_scan3(int* __restrict__ off, const int* __restrict__ blk) {
    int b = blockIdx.x, t = threadIdx.x;
    int i = b * 256 + t;
    if (i <= NN) off[i] += blk[256 + b];
}

__global__ void k_scatter(const int* __restrict__ ei, const int* __restrict__ ea,
                          const int* __restrict__ off, int* __restrict__ cursor,
                          int2* __restrict__ epack) {
    int e = blockIdx.x * 256 + threadIdx.x;
    int src = ei[e];
    int dst = ei[NE + e];
    int a0 = ea[e * 3 + 0], a1 = ea[e * 3 + 1], a2 = ea[e * 3 + 2];
    int p = off[dst] + atomicAdd(&cursor[dst], 1);
    epack[p] = make_int2(src, a0 | (a1 << 3) | (a2 << 6));
}

// ---------------- per-layer aggregation, no atomics -----------------------
// h[n][d] = (1+eps)*x[n][d] + sum_{edges->n} relu(x[src][d] + e_emb[d])
// 256 threads = 2 nodes per block (128 threads each).
__global__ void k_gather(const float* __restrict__ x, const int* __restrict__ off,
                         const int2* __restrict__ epack,
                         const float* __restrict__ bemb,  // [3][8][D] this layer
                         const float* __restrict__ eps, int layer,
                         float* __restrict__ h) {
    int t = threadIdx.x;
    int half = t >> 7, d = t & (DD - 1);
    int n = blockIdx.x * 2 + half;
    int p0 = off[n], p1 = off[n + 1];
    float acc = (1.f + eps[layer]) * x[n * DD + d];
    for (int p = p0; p < p1; ++p) {
        int2 er = epack[p];
        int at = er.y;
        float v = bemb[(at & 7) * DD + d] + bemb[(8 + ((at >> 3) & 7)) * DD + d] +
                  bemb[(16 + (at >> 6)) * DD + d] + x[er.x * DD + d];
        acc += fmaxf(v, 0.f);
    }
    h[n * DD + d] = acc;
}

// Prepack W1/W2 (fp32) into bf16 B-fragment order for mfma_f32_16x16x32_bf16.
__global__ void k_prep(const float* __restrict__ W1, const float* __restrict__ W2,
                       ushort_t* __restrict__ W1P, ushort_t* __restrict__ W2P) {
    int tid = blockIdx.x * 256 + threadIdx.x;  // < NL*65536
    int layer = tid >> 16;
    int r = tid & 65535;
    int half = r >> 15;
    int q = r & 32767;
    int j = q & 7;
    int lane = (q >> 3) & 63;
    if (half == 0) {
        int kk = (q >> 9) & 3;
        int nt = q >> 11;
        int n = nt * 16 + (lane & 15);
        int k = kk * 32 + (lane >> 4) * 8 + j;
        W1P[layer * 32768 + q] = f2b(W1[(layer * DD + k) * 256 + n]);
    } else {
        int kk = (q >> 9) & 7;
        int nt = q >> 12;
        int n = nt * 16 + (lane & 15);
        int k = kk * 32 + (lane >> 4) * 8 + j;
        W2P[layer * 32768 + q] = f2b(W2[(layer * 256 + k) * DD + n]);
    }
}

// Fused MLP on MFMA: x = BNO(relu(BN1(h@W1+b1)) @ W2 + b2) (+relu unless last)
// 16 nodes per block, 256 threads (4 waves).
__global__ void __launch_bounds__(256)
k_mlp_mfma(const float* __restrict__ h, const ushort_t* __restrict__ W1P,
           const ushort_t* __restrict__ W2P, const float* __restrict__ b1,
           const float* __restrict__ g1, const float* __restrict__ bt1,
           const float* __restrict__ m1, const float* __restrict__ v1,
           const float* __restrict__ b2_, const float* __restrict__ gO,
           const float* __restrict__ btO, const float* __restrict__ mO,
           const float* __restrict__ vO, int relu, float* __restrict__ x) {
    __shared__ ushort_t aS[16 * 136];   // 16 rows x 128 (pad +8 halfs)
    __shared__ ushort_t mid[16 * 264];  // 16 rows x 256 (pad +8 halfs)
    int t = threadIdx.x;
    int wave = t >> 6, lane = t & 63;
    int row0 = blockIdx.x * 16;
    int lrow = lane & 15, quad = lane >> 4;

    for (int i = t; i < 2048; i += 256) {
        int r = i >> 7, c = i & 127;
        aS[r * 136 + c] = f2b(h[(row0 + r) * DD + c]);
    }
    __syncthreads();

    f32x4 acc1[4];
#pragma unroll
    for (int i = 0; i < 4; ++i) acc1[i] = (f32x4){0.f, 0.f, 0.f, 0.f};
#pragma unroll
    for (int kk = 0; kk < 4; ++kk) {
        short8 af = *(const short8*)&aS[lrow * 136 + kk * 32 + quad * 8];
#pragma unroll
        for (int i = 0; i < 4; ++i) {
            int nt = wave * 4 + i;
            short8 bf = *(const short8*)&W1P[((nt * 4 + kk) * 64 + lane) * 8];
            acc1[i] = __builtin_amdgcn_mfma_f32_16x16x32_bf16(af, bf, acc1[i], 0, 0, 0);
        }
    }
#pragma unroll
    for (int i = 0; i < 4; ++i) {
        int col = (wave * 4 + i) * 16 + lrow;
        float s1 = g1[col] * rsqrtf(v1[col] + 1e-5f);
        float sh = bt1[col] - (m1[col] - b1[col]) * s1;
#pragma unroll
        for (int r = 0; r < 4; ++r) {
            int row = quad * 4 + r;
            float o = acc1[i][r] * s1 + sh;
            mid[row * 264 + col] = f2b(fmaxf(o, 0.f));
        }
    }
    __syncthreads();

    f32x4 acc2[2];
#pragma unroll
    for (int i = 0; i < 2; ++i) acc2[i] = (f32x4){0.f, 0.f, 0.f, 0.f};
#pragma unroll
    for (int kk = 0; kk < 8; ++kk) {
        short8 af = *(const short8*)&mid[lrow * 264 + kk * 32 + quad * 8];
#pragma unroll
        for (int i = 0; i < 2; ++i) {
            int nt = wave * 2 + i;
            short8 bf = *(const short8*)&W2P[((nt * 8 + kk) * 64 + lane) * 8];
            acc2[i] = __builtin_amdgcn_mfma_f32_16x16x32_bf16(af, bf, acc2[i], 0, 0, 0);
        }
    }
#pragma unroll
    for (int i = 0; i < 2; ++i) {
        int col = (wave * 2 + i) * 16 + lrow;
        float s = gO[col] * rsqrtf(vO[col] + 1e-5f);
        float sh = btO[col] - (mO[col] - b2_[col]) * s;
#pragma unroll
        for (int r = 0; r < 4; ++r) {
            int row = quad * 4 + r;
            float o = acc2[i][r] * s + sh;
            if (relu) o = fmaxf(o, 0.f);
            x[(row0 + row) * DD + col] = o;
        }
    }
}

__global__ void k_pool(const float* __restrict__ x, const int* __restrict__ batch,
                       float* __restrict__ sums, float* __restrict__ cnt) {
    int n = blockIdx.x, d = threadIdx.x;
    int g = batch[n];
    atomicAdd(&sums[g * DD + d], x[n * DD + d]);
    if (d == 0) atomicAdd(&cnt[g], 1.f);
}

__global__ void k_head(const float* __restrict__ sums, const float* __restrict__ cnt,
                       const float* __restrict__ Wp, const float* __restrict__ bp,
                       float* __restrict__ out) {
    int g = blockIdx.x;
    int d = threadIdx.x;
    __shared__ float p[DD];
    float c = fmaxf(cnt[g], 1.f);
    p[d] = sums[g * DD + d] / c;
    __syncthreads();
    if (d < NT) {
        float acc = bp[d];
#pragma unroll 8
        for (int k = 0; k < DD; ++k) acc = fmaf(p[k], Wp[k * NT + d], acc);
        out[g * NT + d] = acc;
    }
}

extern "C" void kernel_launch(void* const* d_in, const int* in_sizes, int n_in,
                              void* d_out, int out_size, void* d_ws, size_t ws_size,
                              hipStream_t stream) {
    const int* x_atom = (const int*)d_in[0];
    const int* edge_index = (const int*)d_in[1];
    const int* edge_attr = (const int*)d_in[2];
    const int* batch = (const int*)d_in[3];
    const float* atom_emb = (const float*)d_in[4];
    const float* bond_emb = (const float*)d_in[5];
    const float* eps = (const float*)d_in[6];
    const float* W1 = (const float*)d_in[7];
    const float* b1 = (const float*)d_in[8];
    const float* g1 = (const float*)d_in[9];
    const float* bt1 = (const float*)d_in[10];
    const float* m1 = (const float*)d_in[11];
    const float* v1 = (const float*)d_in[12];
    const float* W2 = (const float*)d_in[13];
    const float* b2 = (const float*)d_in[14];
    const float* gO = (const float*)d_in[15];
    const float* btO = (const float*)d_in[16];
    const float* mO = (const float*)d_in[17];
    const float* vO = (const float*)d_in[18];
    const float* Wp = (const float*)d_in[19];
    const float* bp = (const float*)d_in[20];

    float* x = (float*)d_ws;                 // N*D
    float* h = x + NN * DD;                  // N*D
    float* sums = h + NN * DD;               // G*D
    float* cnt = sums + NG * DD;             // G
    ushort_t* W1P = (ushort_t*)(cnt + NG);   // NL*32768 bf16
    ushort_t* W2P = W1P + NL * 32768;        // NL*32768 bf16
    int* deg = (int*)(W2P + NL * 32768);     // 40000
    int* off = deg + NN;                     // 40064 (pad to keep alignment)
    int* blk = off + 40064;                  // 512 (sums + exclusive)
    int* cursor = blk + 512;                 // 40000
    int2* epack = (int2*)(cursor + NN);      // 640000 int2 (8B aligned)

    hipMemsetAsync(sums, 0, (NG * DD + NG) * sizeof(float), stream);
    hipMemsetAsync(deg, 0, (NN + 40064 + 512 + NN) * sizeof(int), stream);

    k_prep<<<NL * 65536 / 256, 256, 0, stream>>>(W1, W2, W1P, W2P);
    k_atom<<<NN, DD, 0, stream>>>(x_atom, atom_emb, x);

    // CSR build
    k_hist<<<NE / 256, 256, 0, stream>>>(edge_index, deg);
    k_scan1<<<157, 256, 0, stream>>>(deg, off, blk);
    k_scan2<<<1, 256, 0, stream>>>(blk);
    k_scan3<<<157, 256, 0, stream>>>(off, blk);
    k_scatter<<<NE / 256, 256, 0, stream>>>(edge_index, edge_attr, off, cursor, epack);

    for (int i = 0; i < NL; ++i) {
        k_gather<<<NN / 2, 256, 0, stream>>>(x, off, epack,
                                             bond_emb + (size_t)i * 3 * 8 * DD,
                                             eps, i, h);
        k_mlp_mfma<<<NN / 16, 256, 0, stream>>>(
            h, W1P + (size_t)i * 32768, W2P + (size_t)i * 32768, b1 + i * 256,
            g1 + i * 256, bt1 + i * 256, m1 + i * 256, v1 + i * 256, b2 + i * DD,
            gO + i * DD, btO + i * DD, mO + i * DD, vO + i * DD,
            (i < NL - 1) ? 1 : 0, x);
    }
    k_pool<<<NN, DD, 0, stream>>>(x, batch, sums, cnt);
    k_head<<<NG, DD, 0, stream>>>(sums, cnt, Wp, bp, (float*)d_out);
}